// Round 1
// 501.477 us; speedup vs baseline: 1.1673x; 1.1673x over previous
//
#include <hip/hip_runtime.h>
#include <math.h>

constexpr int N_VN   = 8000;
constexpr int N_CN   = 4000;
constexpr int DV     = 3;
constexpr int DC     = 6;
constexpr int EDGES  = N_VN * DV;   // 24000
constexpr int BATCH  = 1250;
constexpr int BP     = 1280;        // padded batch stride (=320 float4)
constexpr int NUM_ITER = 5;
constexpr float LLR_MAX = 20.0f;
constexpr int TPB    = 320;         // 320 thr x 4 lanes-of-4 = 1280 = BP (5 waves)
constexpr int NPART  = NUM_ITER * N_VN;      // 40000 loss partials
// 2*atanh(clip) with clip = f32(1-1e-7) = 1 - 2^-23: log((2-2^-23)/2^-23)
constexpr float MSGMAX = 16.635532f;
constexpr float FFLOOR = 2e-12f;    // floor on (1-ex): reproduces ref's |t|>=1e-12
// int16 log-domain quantization of mw = clip(msg_vn*w, +-20):
// step 20/32767 = 6.1e-4 abs.  Near the atanh pole the induced relative error
// on the tanh-product is ~2*ex*dmw (ex tiny there) -> msg error <= ~1e-3.
constexpr float QSCALE = 32767.0f / 20.0f;
constexpr float QINV   = 20.0f / 32767.0f;

__device__ __forceinline__ short quant_mw(float mv, float w) {
    float mw = fminf(fmaxf(mv * w, -LLR_MAX), LLR_MAX);
    return (short)__float2int_rn(mw * QSCALE);
}

// ---------------------------------------------------------------- graph build
// cn_edges[c*6+slot] = e   (slot order irrelevant: product commutes)
// epos[e] = c*6+slot       (where VN writes/reads edge e in slot-ordered exn)
__global__ __launch_bounds__(256) void build_graph_k(const int* __restrict__ cn_idx,
                                                     int* __restrict__ cnt,
                                                     int* __restrict__ cn_edges,
                                                     int* __restrict__ epos) {
    int e = blockIdx.x * 256 + threadIdx.x;
    if (e >= EDGES) return;
    int c = cn_idx[e];
    int slot = atomicAdd(&cnt[c], 1);
    cn_edges[c * DC + slot] = e;
    epos[e] = c * DC + slot;
}

// --------------------------------------------------- init: llr out + L = -llr^T
__global__ __launch_bounds__(256) void init_llr_k(const float* __restrict__ noise,
                                                  const int* __restrict__ ebno,
                                                  float* __restrict__ llr_out,
                                                  float* __restrict__ L) {
    __shared__ float tile[32][33];
    __shared__ float hs[2];
    int tx = threadIdx.x, ty = threadIdx.y;
    if (tx == 0 && ty == 0) {
        double sig2 = 2.0 * pow(10.0, (double)ebno[0] * 0.1);  // 4/no
        hs[0] = (float)(sig2 * 0.5);
        hs[1] = (float)sqrt(sig2);
    }
    __syncthreads();
    float h = hs[0], s = hs[1];
    int vbase = blockIdx.x * 32;
    int bbase = blockIdx.y * 32;
    #pragma unroll
    for (int j = 0; j < 4; ++j) {
        int v = vbase + tx;
        int b = bbase + ty + j * 8;
        if (b < BATCH) {
            float val = noise[b * N_VN + v];
            tile[ty + j * 8][tx] = val;
            llr_out[b * N_VN + v] = -h + s * val;
        }
    }
    __syncthreads();
    #pragma unroll
    for (int j = 0; j < 4; ++j) {
        int b = bbase + tx;
        int v = vbase + ty + j * 8;
        if (b < BATCH) L[v * BP + b] = h - s * tile[tx][ty + j * 8];  // L=-llr^T
    }
}

// ------------------ iter 0 CN: products straight from L, write tprod ONLY
__global__ __launch_bounds__(TPB) void cn_first_k(const float* __restrict__ L,
                                                  const float* __restrict__ weights,
                                                  const int* __restrict__ cn_edges,
                                                  float* __restrict__ tprod) {
    int c = blockIdx.x;
    int b0 = threadIdx.x * 4;
    float num[4] = {1.f, 1.f, 1.f, 1.f}, den[4] = {1.f, 1.f, 1.f, 1.f};
    unsigned sx[4] = {0u, 0u, 0u, 0u};
    #pragma unroll
    for (int j = 0; j < DC; ++j) {
        int e = cn_edges[c * DC + j];            // uniform -> scalar load
        int v = e; if (v >= 2 * N_VN) v -= 2 * N_VN; else if (v >= N_VN) v -= N_VN;
        float w = weights[e];
        float4 Lv = *(const float4*)(L + (size_t)v * BP + b0);
        float a[4] = {Lv.x, Lv.y, Lv.z, Lv.w};
        #pragma unroll
        for (int k = 0; k < 4; ++k) {
            float mw = fminf(fmaxf(a[k] * w, -LLR_MAX), LLR_MAX);
            float ex = __expf(-fabsf(mw));
            num[k] *= fmaxf(1.0f - ex, FFLOOR);
            den[k] *= 1.0f + ex;
            sx[k] ^= __float_as_uint(mw);
        }
    }
    float o[4];
    #pragma unroll
    for (int k = 0; k < 4; ++k) {
        float T = __fdividef(num[k], den[k]);    // >= 0 (may underflow to +0)
        o[k] = __uint_as_float(__float_as_uint(T) | (sx[k] & 0x80000000u));
    }
    *(float4*)(tprod + (size_t)c * BP + b0) = make_float4(o[0], o[1], o[2], o[3]);
}

// ----------------- CN: slot-ordered int16 exn -> fully contiguous reads,
// no index loads.  Decode mw, recompute ex = exp(-|mw|).
__global__ __launch_bounds__(TPB) void cn_k(const short* __restrict__ exn,
                                            float* __restrict__ tprod) {
    int c = blockIdx.x;
    int b0 = threadIdx.x * 4;
    const short* base = exn + (size_t)c * DC * BP + b0;
    float num[4] = {1.f, 1.f, 1.f, 1.f}, den[4] = {1.f, 1.f, 1.f, 1.f};
    unsigned sx[4] = {0u, 0u, 0u, 0u};
    #pragma unroll
    for (int j = 0; j < DC; ++j) {
        short4 q4 = *(const short4*)(base + j * BP);
        short qa[4] = {q4.x, q4.y, q4.z, q4.w};
        #pragma unroll
        for (int k = 0; k < 4; ++k) {
            float mw = (float)qa[k] * QINV;
            float ex = __expf(-fabsf(mw));
            num[k] *= fmaxf(1.0f - ex, FFLOOR);
            den[k] *= 1.0f + ex;
            sx[k] ^= __float_as_uint(mw);
        }
    }
    float o[4];
    #pragma unroll
    for (int k = 0; k < 4; ++k) {
        float T = __fdividef(num[k], den[k]);
        o[k] = __uint_as_float(__float_as_uint(T) | (sx[k] & 0x80000000u));
    }
    *(float4*)(tprod + (size_t)c * BP + b0) = make_float4(o[0], o[1], o[2], o[3]);
}

// ------------------------------------------------------------------ VN update
template <bool FIRST, bool LAST>
__global__ __launch_bounds__(TPB) void vn_k(short* __restrict__ exn,
                                            const float* __restrict__ L,
                                            const float* __restrict__ weights,
                                            const int* __restrict__ cn_idx,
                                            const int* __restrict__ epos,
                                            const float* __restrict__ tprod,
                                            float* __restrict__ xtot,
                                            float* __restrict__ loss_part) {
    int v = blockIdx.x;
    int tid = threadIdx.x;
    int b0 = tid * 4;
    float4 Lv4 = *(const float4*)(L + (size_t)v * BP + b0);
    float Lv[4] = {Lv4.x, Lv4.y, Lv4.z, Lv4.w};
    float xt[4] = {Lv[0], Lv[1], Lv[2], Lv[3]};
    float mc[DV][4];
    float wl[DV];
    int   pl[DV];
    #pragma unroll
    for (int l = 0; l < DV; ++l) {
        int e = v + l * N_VN;                // vn_idx[e] == e % N_VN
        int c = cn_idx[e];                   // uniform -> scalar load
        pl[l] = epos[e];                     // uniform -> scalar load
        wl[l] = weights[e];
        float mwv[4];
        if (FIRST) {
            #pragma unroll
            for (int k = 0; k < 4; ++k)
                mwv[k] = fminf(fmaxf(Lv[k] * wl[l], -LLR_MAX), LLR_MAX);
        } else {
            short4 q4 = *(const short4*)(exn + (size_t)pl[l] * BP + b0);
            short qa[4] = {q4.x, q4.y, q4.z, q4.w};
            #pragma unroll
            for (int k = 0; k < 4; ++k) mwv[k] = (float)qa[k] * QINV;
        }
        float4 T4 = *(const float4*)(tprod + (size_t)c * BP + b0);
        float Ta[4] = {T4.x, T4.y, T4.z, T4.w};
        #pragma unroll
        for (int k = 0; k < 4; ++k) {
            float ex = __expf(-fabsf(mwv[k]));
            float A  = fabsf(Ta[k]);
            float f  = fmaxf(1.0f - ex, FFLOOR);
            float g  = fmaf(A, ex, A);               // A*(1+ex)
            // 2*atanh(p), p = prod_others: (1+p)/(1-p) == (f+g)/(f-g)
            float r  = __fdividef(f + g, f - g);
            float ma = fminf(__logf(r), MSGMAX);     // inf/NaN corner -> clamp
            unsigned sg = (__float_as_uint(mwv[k]) ^ __float_as_uint(Ta[k]))
                          & 0x80000000u;
            float msg = __uint_as_float(__float_as_uint(ma) ^ sg);
            mc[l][k] = msg;
            xt[k] += msg;
        }
    }
    if (!LAST) {
        // next-iteration quantized mw: msg_vn' = xt - mc
        #pragma unroll
        for (int l = 0; l < DV; ++l) {
            short o[4];
            #pragma unroll
            for (int k = 0; k < 4; ++k) o[k] = quant_mw(xt[k] - mc[l][k], wl[l]);
            *(short4*)(exn + (size_t)pl[l] * BP + b0) = make_short4(o[0], o[1], o[2], o[3]);
        }
    } else {
        if (b0 + 3 < BATCH) {                // xtot stride 1250 (8B aligned only)
            *(float2*)(xtot + (size_t)v * BATCH + b0)     = make_float2(xt[0], xt[1]);
            *(float2*)(xtot + (size_t)v * BATCH + b0 + 2) = make_float2(xt[2], xt[3]);
        } else {
            #pragma unroll
            for (int k = 0; k < 4; ++k)
                if (b0 + k < BATCH) xtot[(size_t)v * BATCH + b0 + k] = xt[k];
        }
    }
    // loss partial (masked to valid batch), softplus(-xt) stable, hw-trans only
    float sp = 0.0f;
    #pragma unroll
    for (int k = 0; k < 4; ++k)
        if (b0 + k < BATCH) {
            float x = xt[k];
            sp += fmaxf(-x, 0.0f) + __logf(1.0f + __expf(-fabsf(x)));
        }
    #pragma unroll
    for (int off = 32; off > 0; off >>= 1)
        sp += __shfl_down(sp, off, 64);
    __shared__ float red[5];
    int lane = tid & 63, wid = tid >> 6;
    if (lane == 0) red[wid] = sp;
    __syncthreads();
    if (tid == 0)
        loss_part[blockIdx.x] = red[0] + red[1] + red[2] + red[3] + red[4];
}

// -------------------------------------------------- c_hat = -x_tot^T (tiled)
__global__ __launch_bounds__(256) void transpose_chat_k(const float* __restrict__ xtot,
                                                        float* __restrict__ chat) {
    __shared__ float tile[32][33];
    int bbase = blockIdx.x * 32;
    int vbase = blockIdx.y * 32;
    int tx = threadIdx.x, ty = threadIdx.y;
    #pragma unroll
    for (int j = 0; j < 4; ++j) {
        int v = vbase + ty + j * 8;
        int b = bbase + tx;
        if (b < BATCH) tile[ty + j * 8][tx] = xtot[(size_t)v * BATCH + b];
    }
    __syncthreads();
    #pragma unroll
    for (int j = 0; j < 4; ++j) {
        int b = bbase + ty + j * 8;
        int v = vbase + tx;
        if (b < BATCH) chat[(size_t)b * N_VN + v] = -tile[tx][ty + j * 8];
    }
}

// ------------------------------------------------- loss: two-stage reduction
__global__ __launch_bounds__(256) void loss_stage1_k(const float* __restrict__ lp,
                                                     double* __restrict__ part) {
    double s = 0.0;
    for (int i = blockIdx.x * 256 + threadIdx.x; i < NPART; i += 64 * 256)
        s += (double)lp[i];
    #pragma unroll
    for (int off = 32; off > 0; off >>= 1)
        s += __shfl_down(s, off, 64);
    __shared__ double red[4];
    int lane = threadIdx.x & 63, wid = threadIdx.x >> 6;
    if (lane == 0) red[wid] = s;
    __syncthreads();
    if (threadIdx.x == 0) part[blockIdx.x] = red[0] + red[1] + red[2] + red[3];
}

__global__ __launch_bounds__(64) void loss_stage2_k(const double* __restrict__ part,
                                                    float* __restrict__ out_loss) {
    double s = part[threadIdx.x];
    #pragma unroll
    for (int off = 32; off > 0; off >>= 1)
        s += __shfl_down(s, off, 64);
    if (threadIdx.x == 0)
        out_loss[0] = (float)(s / ((double)NUM_ITER * (double)BATCH * (double)N_VN));
}

// ---------------------------------------------------------------------- launch
extern "C" void kernel_launch(void* const* d_in, const int* in_sizes, int n_in,
                              void* d_out, int out_size, void* d_ws, size_t ws_size,
                              hipStream_t stream) {
    const float* noise   = (const float*)d_in[0];   // (1250, 8000)
    const float* weights = (const float*)d_in[1];   // (24000,)
    // d_in[2] = vn_idx (unused: vn_idx[e] == e % 8000 by construction)
    const int* cn_idx    = (const int*)d_in[3];     // (24000,)
    const int* ebno      = (const int*)d_in[4];     // scalar int

    float* out      = (float*)d_out;
    float* out_c    = out;                 // (1250,8000) zeros
    float* out_chat = out + 10000000;      // (1250,8000)
    float* out_llr  = out + 20000000;      // (1250,8000)
    float* out_loss = out + 30000000;      // scalar

    // workspace layout (~123.3 MB)
    char* ws = (char*)d_ws;
    short*  exn       = (short*)(ws);                    // 24000*1280*2 = 61,440,000
    float*  L         = (float*)(ws + 61440000);         //  8000*1280*4 = 40,960,000
    float*  tprod     = (float*)(ws + 102400000);        //  4000*1280*4 = 20,480,000
    int*    cn_edges  = (int*)(ws + 122880000);          //  4000*6*4    =     96,000
    int*    epos      = (int*)(ws + 122976000);          // 24000*4      =     96,000
    int*    cn_cnt    = (int*)(ws + 123072000);          //  4000*4      =     16,000
    float*  loss_part = (float*)(ws + 123088000);        //  5*8000*4    =    160,000
    double* loss_p2   = (double*)(ws + 123248000);       //  64*8        =        512
    float*  xtot      = out_c;  // stride 1250 = exactly 10M floats, no chat overlap

    hipMemsetAsync(cn_cnt, 0, N_CN * sizeof(int), stream);

    build_graph_k<<<dim3((EDGES + 255) / 256), dim3(256), 0, stream>>>(cn_idx, cn_cnt, cn_edges, epos);
    init_llr_k<<<dim3(N_VN / 32, (BATCH + 31) / 32), dim3(32, 8), 0, stream>>>(noise, ebno, out_llr, L);

    for (int it = 0; it < NUM_ITER; ++it) {
        float* lp = loss_part + it * N_VN;   // write-only private slots
        if (it == 0)
            cn_first_k<<<dim3(N_CN), dim3(TPB), 0, stream>>>(L, weights, cn_edges, tprod);
        else
            cn_k<<<dim3(N_CN), dim3(TPB), 0, stream>>>(exn, tprod);
        if (it == 0)
            vn_k<true , false><<<dim3(N_VN), dim3(TPB), 0, stream>>>(exn, L, weights, cn_idx, epos, tprod, xtot, lp);
        else if (it == NUM_ITER - 1)
            vn_k<false, true ><<<dim3(N_VN), dim3(TPB), 0, stream>>>(exn, L, weights, cn_idx, epos, tprod, xtot, lp);
        else
            vn_k<false, false><<<dim3(N_VN), dim3(TPB), 0, stream>>>(exn, L, weights, cn_idx, epos, tprod, xtot, lp);
    }

    transpose_chat_k<<<dim3((BATCH + 31) / 32, N_VN / 32), dim3(32, 8), 0, stream>>>(xtot, out_chat);
    hipMemsetAsync(out_c, 0, 10000000 * sizeof(float), stream);  // c = zeros (after xtot read)
    loss_stage1_k<<<dim3(64), dim3(256), 0, stream>>>(loss_part, loss_p2);
    loss_stage2_k<<<dim3(1), dim3(64), 0, stream>>>(loss_p2, out_loss);
}

// Round 2
// 400.497 us; speedup vs baseline: 1.4616x; 1.2521x over previous
//
#include <hip/hip_runtime.h>
#include <math.h>

constexpr int N_VN   = 8000;
constexpr int N_CN   = 4000;
constexpr int DV     = 3;
constexpr int DC     = 6;
constexpr int EDGES  = N_VN * DV;   // 24000
constexpr int BATCH  = 1250;
constexpr int NUM_ITER = 5;
constexpr float LLR_MAX = 20.0f;
// 2*atanh(clip) with clip = f32(1-1e-7) = 1 - 2^-23: log((2-2^-23)/2^-23)
constexpr float MSGMAX = 16.635532f;
constexpr float FFLOOR = 2e-12f;    // floor on (1-ex): reproduces ref's |t|>=1e-12

constexpr int SLOT_STRIDE = 7;      // 6 edge slots + 1 pad word per CN:
                                    // lane stride 7 words, coprime with 32 banks
constexpr int MTPB  = 1024;         // mega block: 16 waves, 1 block/CU (LDS-capped)
constexpr int VNPT  = (N_VN + MTPB - 1) / MTPB;   // 8 VNs per thread

// Packed edge stat: ex = exp(-|mw|) in (0,1], sign bit = sign(mw).
__device__ __forceinline__ float pack_ex(float mv, float w) {
    float mw = fminf(fmaxf(mv * w, -LLR_MAX), LLR_MAX);
    float ex = __expf(-fabsf(mw));
    unsigned sgn = __float_as_uint(mw) & 0x80000000u;
    return __uint_as_float(__float_as_uint(ex) | sgn);
}

// ---------------------------------------------------------------- graph build
// epos[e] = c*7 + slot : word index of edge e in the slot-ordered LDS edge buf.
// Slot order from atomics is arbitrary -> irrelevant (CN product commutes).
__global__ __launch_bounds__(256) void build_graph_k(const int* __restrict__ cn_idx,
                                                     int* __restrict__ cnt,
                                                     int* __restrict__ epos) {
    int e = blockIdx.x * 256 + threadIdx.x;
    if (e >= EDGES) return;
    int c = cn_idx[e];
    int slot = atomicAdd(&cnt[c], 1);
    epos[e] = c * SLOT_STRIDE + slot;
}

// ------------------------------------------------------------- the mega kernel
// One block per batch element. Whole 5-iteration BP in LDS:
//   eL[28000]  : per-edge value; VN->CN direction holds signed-ex,
//                CN->VN direction holds msg_cn.  In-place role swap.
//   L          : per-thread registers (VN ownership identical in all phases).
// HBM: read noise row (32 KB), write llr row + chat row (32 KB each). That's it.
__global__ __launch_bounds__(MTPB) void bp_mega_k(const float* __restrict__ noise,
                                                  const float* __restrict__ weights,
                                                  const int* __restrict__ epos,
                                                  const int* __restrict__ ebno,
                                                  float* __restrict__ llr_out,
                                                  float* __restrict__ chat_out,
                                                  float* __restrict__ loss_part) {
    __shared__ float eL[N_CN * SLOT_STRIDE];   // 112000 B
    __shared__ float hs[2];
    __shared__ float red[MTPB / 64];

    const int b   = blockIdx.x;
    const int tid = threadIdx.x;

    if (tid == 0) {
        double sig2 = 2.0 * pow(10.0, (double)ebno[0] * 0.1);  // 4/no
        hs[0] = (float)(sig2 * 0.5);
        hs[1] = (float)sqrt(sig2);
    }
    __syncthreads();
    const float h = hs[0], s = hs[1];

    const float* nrow = noise    + (size_t)b * N_VN;
    float*       lrow = llr_out  + (size_t)b * N_VN;
    float*       crow = chat_out + (size_t)b * N_VN;

    // ---- prologue: llr out, L in regs, iter-0 edge init (pack_ex(L*w))
    float Lreg[VNPT];
    int   pp[VNPT][DV];
    float ww[VNPT][DV];
    #pragma unroll
    for (int r = 0; r < VNPT; ++r) {
        int v = tid + r * MTPB;
        if (v < N_VN) {
            float nv  = nrow[v];
            float llr = fmaf(s, nv, -h);
            lrow[v]   = llr;
            Lreg[r]   = -llr;                    // L = -llr
            #pragma unroll
            for (int l = 0; l < DV; ++l) {
                int e = v + l * N_VN;            // vn_idx[e] == e % N_VN
                pp[r][l] = epos[e];
                ww[r][l] = weights[e];
                eL[pp[r][l]] = pack_ex(Lreg[r], ww[r][l]);
            }
        }
    }

    float lossacc = 0.0f;
    for (int it = 0; it < NUM_ITER; ++it) {
        __syncthreads();                         // edge buf holds signed-ex
        // ---- CN phase: per-edge leave-one-out message, in-place
        for (int c = tid; c < N_CN; c += MTPB) {
            float* base = eL + c * SLOT_STRIDE;
            float se[DC], f[DC], d[DC];
            float num = 1.0f, den = 1.0f;
            unsigned sx = 0u;
            #pragma unroll
            for (int j = 0; j < DC; ++j) {
                se[j] = base[j];
                float ex = fabsf(se[j]);
                f[j] = fmaxf(1.0f - ex, FFLOOR);
                d[j] = 1.0f + ex;
                num *= f[j];
                den *= d[j];
                sx  ^= __float_as_uint(se[j]);
            }
            float T = __fdividef(num, den);      // |prod of all t| (may underflow to +0)
            #pragma unroll
            for (int j = 0; j < DC; ++j) {
                // 2*atanh(p_j), p_j = T/t_j: (1+p)/(1-p) == (f_j + T*d_j)/(f_j - T*d_j)
                float g  = T * d[j];
                float r  = __fdividef(f[j] + g, f[j] - g);
                float ma = fminf(__logf(r), MSGMAX);   // inf/NaN corner -> clamp
                unsigned sg = (sx ^ __float_as_uint(se[j])) & 0x80000000u;
                base[j] = __uint_as_float(__float_as_uint(ma) ^ sg);
            }
        }
        __syncthreads();                         // edge buf holds msg_cn
        // ---- VN phase: xt, loss, next-iteration signed-ex (in-place)
        const bool wr = (it != NUM_ITER - 1);
        #pragma unroll
        for (int r = 0; r < VNPT; ++r) {
            int v = tid + r * MTPB;
            if (v < N_VN) {
                float m0 = eL[pp[r][0]];
                float m1 = eL[pp[r][1]];
                float m2 = eL[pp[r][2]];
                float xt = Lreg[r] + m0 + m1 + m2;
                if (wr) {
                    eL[pp[r][0]] = pack_ex(xt - m0, ww[r][0]);
                    eL[pp[r][1]] = pack_ex(xt - m1, ww[r][1]);
                    eL[pp[r][2]] = pack_ex(xt - m2, ww[r][2]);
                } else {
                    crow[v] = -xt;               // c_hat, coalesced
                }
                // softplus(-xt), stable
                lossacc += fmaxf(-xt, 0.0f) + __logf(1.0f + __expf(-fabsf(xt)));
            }
        }
    }

    // ---- block loss reduction -> loss_part[b]
    #pragma unroll
    for (int off = 32; off > 0; off >>= 1)
        lossacc += __shfl_down(lossacc, off, 64);
    int lane = tid & 63, wid = tid >> 6;
    if (lane == 0) red[wid] = lossacc;
    __syncthreads();
    if (tid == 0) {
        float ssum = 0.0f;
        #pragma unroll
        for (int i = 0; i < MTPB / 64; ++i) ssum += red[i];
        loss_part[b] = ssum;
    }
}

// ---------------------------------------------------- final loss over 1250 blocks
__global__ __launch_bounds__(256) void loss_final_k(const float* __restrict__ lp,
                                                    float* __restrict__ out_loss) {
    double s = 0.0;
    for (int i = threadIdx.x; i < BATCH; i += 256) s += (double)lp[i];
    #pragma unroll
    for (int off = 32; off > 0; off >>= 1)
        s += __shfl_down(s, off, 64);
    __shared__ double red[4];
    int lane = threadIdx.x & 63, wid = threadIdx.x >> 6;
    if (lane == 0) red[wid] = s;
    __syncthreads();
    if (threadIdx.x == 0)
        out_loss[0] = (float)((red[0] + red[1] + red[2] + red[3]) /
                              ((double)NUM_ITER * (double)BATCH * (double)N_VN));
}

// ---------------------------------------------------------------------- launch
extern "C" void kernel_launch(void* const* d_in, const int* in_sizes, int n_in,
                              void* d_out, int out_size, void* d_ws, size_t ws_size,
                              hipStream_t stream) {
    const float* noise   = (const float*)d_in[0];   // (1250, 8000)
    const float* weights = (const float*)d_in[1];   // (24000,)
    // d_in[2] = vn_idx (unused: vn_idx[e] == e % 8000 by construction)
    const int* cn_idx    = (const int*)d_in[3];     // (24000,)
    const int* ebno      = (const int*)d_in[4];     // scalar int

    float* out      = (float*)d_out;
    float* out_c    = out;                 // (1250,8000) zeros
    float* out_chat = out + 10000000;      // (1250,8000)
    float* out_llr  = out + 20000000;      // (1250,8000)
    float* out_loss = out + 30000000;      // scalar

    // workspace (tiny now): epos, cn_cnt, loss_part
    char* ws = (char*)d_ws;
    int*   epos      = (int*)(ws);                 // 24000*4 = 96,000
    int*   cn_cnt    = (int*)(ws + 96000);         //  4000*4 = 16,000
    float* loss_part = (float*)(ws + 112000);      //  1250*4 =  5,000

    hipMemsetAsync(cn_cnt, 0, N_CN * sizeof(int), stream);
    build_graph_k<<<dim3((EDGES + 255) / 256), dim3(256), 0, stream>>>(cn_idx, cn_cnt, epos);

    bp_mega_k<<<dim3(BATCH), dim3(MTPB), 0, stream>>>(noise, weights, epos, ebno,
                                                      out_llr, out_chat, loss_part);

    loss_final_k<<<dim3(1), dim3(256), 0, stream>>>(loss_part, out_loss);
    hipMemsetAsync(out_c, 0, 10000000 * sizeof(float), stream);  // c = zeros
}